// Round 7
// baseline (68.648 us; speedup 1.0000x reference)
//
#include <hip/hip_runtime.h>
#include <hip/hip_bf16.h>

typedef __attribute__((ext_vector_type(8))) short bf16x8;
typedef __attribute__((ext_vector_type(4))) float f32x4;

__device__ __forceinline__ short f2bf(float x) {
    __hip_bfloat16 t = __float2bfloat16(x);
    return __builtin_bit_cast(short, t);
}

// B=16, N=4096, K=16, hidden=64, dim=64
// R7: xyz staged in LDS (48KB per block, block pinned to one batch) so
// neighbor gathers never touch L2 -> plain stores can't pollute the reads.
// Plain 1KB-contiguous dwordx4 stores (the fast fill-kernel path, ~7 TB/s).
// Mapping: 512 blocks; batch = blk>>5; wave slot = (blk&31)*4+warp (0..127);
// wave's groups: n = slot*32 + t, t=0..31 (contiguous 128KB store range).

#define USE_NT 0

__global__ __launch_bounds__(256, 2) void ppe_kernel(
    const float* __restrict__ xyz,   // [16,4096,3]
    const float* __restrict__ dist,  // [16,4096,16]
    const float* __restrict__ W1,    // [10,64]
    const float* __restrict__ b1,    // [64]
    const float* __restrict__ W2,    // [64,64]
    const float* __restrict__ b2,    // [64]
    const int*   __restrict__ idx,   // [16,4096,16] (int32)
    float* __restrict__ out)         // [16,4096,16,64]
{
    __shared__ float lds_xyz[4096 * 3];   // 48 KB: this block's batch slice
    __shared__ float sbuf[4][1024];       // 16 KB: per-wave store staging

    const int lane = threadIdx.x & 63;
    const int warp = threadIdx.x >> 6;
    const int u    = lane >> 4;   // 0..3
    const int p    = lane & 15;   // 0..15

    const int batch = blockIdx.x >> 5;                  // 0..15
    const int slot  = ((blockIdx.x & 31) << 2) | warp;  // 0..127

    float* const ws = &sbuf[warp][0];

    // ---- cooperative xyz -> LDS (12288 floats, coalesced dwordx4) ----
    {
        const float* xb = xyz + (size_t)batch * 12288;
#pragma unroll
        for (int i = 0; i < 12; ++i) {
            const int c = i * 256 + threadIdx.x;
            *(f32x4*)&lds_xyz[c * 4] = *(const f32x4*)&xb[c * 4];
        }
    }

    // ---- persistent weight fragments (identical to R5) ----
    bf16x8 w1f[4];
#pragma unroll
    for (int t = 0; t < 4; ++t) {
        const int hu = 16 * t + p;
#pragma unroll
        for (int j = 0; j < 8; ++j) {
            float coef;
            if (j < 3)      coef = W1[j * 64 + hu] + W1[(6 + j) * 64 + hu];
            else if (j < 6) coef = W1[j * 64 + hu] - W1[(j + 3) * 64 + hu];
            else if (j == 6) coef = W1[9 * 64 + hu];
            else             coef = b1[hu];
            w1f[t][j] = (u == 0) ? f2bf(coef) : (short)0;
        }
    }

    bf16x8 w2f[4][2];
#pragma unroll
    for (int dt = 0; dt < 4; ++dt)
#pragma unroll
        for (int kt = 0; kt < 2; ++kt)
#pragma unroll
            for (int j = 0; j < 8; ++j) {
                const int unit = 32 * kt + 16 * (j >> 2) + 4 * u + (j & 3);
                w2f[dt][kt][j] = f2bf(W2[unit * 64 + 16 * dt + p]);
            }

    float b2r[4][4];
#pragma unroll
    for (int dt = 0; dt < 4; ++dt)
#pragma unroll
        for (int r = 0; r < 4; ++r)
            b2r[dt][r] = b2[16 * dt + 4 * u + r];

    const short one_bf = f2bf(1.0f);

    __syncthreads();   // xyz resident

    // ---- main loop: 32 contiguous groups per wave ----
    const int gbase = batch * 4096 + slot * 32;

    // prologue: idx/dist for t=0
    int   rowC = gbase * 16 + p;
    int   nbC  = idx[rowC];
    float dCv  = dist[rowC];

    for (int t = 0; t < 32; ++t) {
        const int g = gbase + t;

        // ---- 1. prefetch idx/dist for t+1 (streaming, 64B/instr) ----
        const int tn   = (t < 31) ? t + 1 : t;
        const int rowN = (gbase + tn) * 16 + p;
        int   nbN = idx[rowN];
        float dNv = dist[rowN];

        // ---- 2. gather from LDS ----
        const int n = g & 4095;                  // center point (wave-uniform)
        const float c0 = lds_xyz[3 * n    ];
        const float c1 = lds_xyz[3 * n + 1];
        const float c2 = lds_xyz[3 * n + 2];
        const float n0 = lds_xyz[3 * nbC    ];
        const float n1 = lds_xyz[3 * nbC + 1];
        const float n2 = lds_xyz[3 * nbC + 2];

        // ---- 3. layer-1 MFMA ----
        bf16x8 fa;
        fa[0] = f2bf(c0); fa[1] = f2bf(c1); fa[2] = f2bf(c2);
        fa[3] = f2bf(n0); fa[4] = f2bf(n1); fa[5] = f2bf(n2);
        fa[6] = f2bf(dCv); fa[7] = one_bf;

        f32x4 acc1[4];
#pragma unroll
        for (int tt = 0; tt < 4; ++tt) {
            acc1[tt] = (f32x4){0.f, 0.f, 0.f, 0.f};
            acc1[tt] = __builtin_amdgcn_mfma_f32_16x16x32_bf16(w1f[tt], fa, acc1[tt], 0, 0, 0);
            acc1[tt][0] = fmaxf(acc1[tt][0], 0.f);
            acc1[tt][1] = fmaxf(acc1[tt][1], 0.f);
            acc1[tt][2] = fmaxf(acc1[tt][2], 0.f);
            acc1[tt][3] = fmaxf(acc1[tt][3], 0.f);
        }

        // ---- 4. layer-2 B-frag directly from acc1 (permutation-matched) ----
        bf16x8 hb[2];
#pragma unroll
        for (int kt = 0; kt < 2; ++kt)
#pragma unroll
            for (int j = 0; j < 8; ++j)
                hb[kt][j] = f2bf(acc1[2 * kt + (j >> 2)][j & 3]);

        // ---- 5. layer-2 MFMA, bias in C-init ----
        f32x4 acc2[4];
#pragma unroll
        for (int dt = 0; dt < 4; ++dt) {
            acc2[dt] = (f32x4){b2r[dt][0], b2r[dt][1], b2r[dt][2], b2r[dt][3]};
            acc2[dt] = __builtin_amdgcn_mfma_f32_16x16x32_bf16(w2f[dt][0], hb[0], acc2[dt], 0, 0, 0);
            acc2[dt] = __builtin_amdgcn_mfma_f32_16x16x32_bf16(w2f[dt][1], hb[1], acc2[dt], 0, 0, 0);
        }

        // ---- 6. transpose via LDS (swizzled, conflict-free) ----
#pragma unroll
        for (int dt = 0; dt < 4; ++dt) {
            const int col = (16 * dt + 4 * u) ^ ((p & 1) << 4);
            *(f32x4*)&ws[p * 64 + col] = acc2[dt];
        }

        // ---- 7. LDS -> 4x 1KB contiguous dwordx4 stores ----
        float* const obase = out + (size_t)g * 1024;
#pragma unroll
        for (int i = 0; i < 4; ++i) {
            const int pt = 4 * i + u;
            f32x4 v = *(const f32x4*)&ws[pt * 64 + ((4 * p) ^ ((u & 1) << 4))];
#if USE_NT
            __builtin_nontemporal_store(v, (f32x4*)&obase[i * 256 + lane * 4]);
#else
            *(f32x4*)&obase[i * 256 + lane * 4] = v;
#endif
        }

        // ---- 8. rotate ----
        nbC = nbN; dCv = dNv;
    }
}

extern "C" void kernel_launch(void* const* d_in, const int* in_sizes, int n_in,
                              void* d_out, int out_size, void* d_ws, size_t ws_size,
                              hipStream_t stream) {
    const float* xyz  = (const float*)d_in[0];
    const float* dist = (const float*)d_in[1];
    const float* W1   = (const float*)d_in[2];
    const float* b1   = (const float*)d_in[3];
    const float* W2   = (const float*)d_in[4];
    const float* b2   = (const float*)d_in[5];
    const int*   idx  = (const int*)d_in[6];
    float* out = (float*)d_out;

    ppe_kernel<<<dim3(512), dim3(256), 0, stream>>>(xyz, dist, W1, b1, W2, b2, idx, out);
}

// Round 8
// 61.067 us; speedup vs baseline: 1.1242x; 1.1242x over previous
//
#include <hip/hip_runtime.h>
#include <hip/hip_bf16.h>

typedef __attribute__((ext_vector_type(8))) short bf16x8;
typedef __attribute__((ext_vector_type(4))) float f32x4;

__device__ __forceinline__ short f2bf(float x) {
    __hip_bfloat16 t = __float2bfloat16(x);
    return __builtin_bit_cast(short, t);
}

// B=16, N=4096, K=16, hidden=64, dim=64
// R8: test the HBM row-locality theory for the NT-store 4.96 TB/s cap.
// Wave owns 32 CONTIGUOUS groups (gbase=wid*32); per iteration computes 4
// groups (MFMA path identical to R5), parks 16 KB in LDS, then issues one
// burst of 16 back-to-back NT dwordx4 = 16 KB contiguous. Each wave's store
// stream is 128 KB fully sequential (vs 4 KB scattered fronts before).
// grid 512x256 = 2048 waves; LDS 64 KB/block, 2 blocks/CU (8 waves/CU --
// same occupancy that produced 54.1 us, so burst size is the only variable).

__global__ __launch_bounds__(256, 2) void ppe_kernel(
    const float* __restrict__ xyz,   // [16,4096,3]
    const float* __restrict__ dist,  // [16,4096,16]
    const float* __restrict__ W1,    // [10,64]
    const float* __restrict__ b1,    // [64]
    const float* __restrict__ W2,    // [64,64]
    const float* __restrict__ b2,    // [64]
    const int*   __restrict__ idx,   // [16,4096,16] (int32)
    float* __restrict__ out)         // [16,4096,16,64]
{
    __shared__ float sbuf[4][4096];  // 16 KB per wave (4 group slices)

    const int lane = threadIdx.x & 63;
    const int warp = threadIdx.x >> 6;
    const int wid  = (blockIdx.x * blockDim.x + threadIdx.x) >> 6; // 0..2047
    const int u    = lane >> 4;   // 0..3
    const int p    = lane & 15;   // 0..15

    float* const ws = &sbuf[warp][0];

    // ---- persistent weight fragments (identical to R5) ----
    bf16x8 w1f[4];
#pragma unroll
    for (int t = 0; t < 4; ++t) {
        const int hu = 16 * t + p;
#pragma unroll
        for (int j = 0; j < 8; ++j) {
            float coef;
            if (j < 3)      coef = W1[j * 64 + hu] + W1[(6 + j) * 64 + hu];
            else if (j < 6) coef = W1[j * 64 + hu] - W1[(j + 3) * 64 + hu];
            else if (j == 6) coef = W1[9 * 64 + hu];
            else             coef = b1[hu];
            w1f[t][j] = (u == 0) ? f2bf(coef) : (short)0;
        }
    }

    bf16x8 w2f[4][2];
#pragma unroll
    for (int dt = 0; dt < 4; ++dt)
#pragma unroll
        for (int kt = 0; kt < 2; ++kt)
#pragma unroll
            for (int j = 0; j < 8; ++j) {
                const int unit = 32 * kt + 16 * (j >> 2) + 4 * u + (j & 3);
                w2f[dt][kt][j] = f2bf(W2[unit * 64 + 16 * dt + p]);
            }

    float b2r[4][4];
#pragma unroll
    for (int dt = 0; dt < 4; ++dt)
#pragma unroll
        for (int r = 0; r < 4; ++r)
            b2r[dt][r] = b2[16 * dt + 4 * u + r];

    const short one_bf = f2bf(1.0f);
    const int gbase = wid * 32;

    // ---- pipeline state, 4 slots ----
    float cC[4][3], nC[4][3], dC[4];   // operands for current batch
    int   nbN[4];  float dN[4];        // idx/dist for next batch

    // prologue: batch 0 operands + batch 1 idx/dist
#pragma unroll
    for (int s = 0; s < 4; ++s) {
        const int g  = gbase + s;
        const int r0 = g * 16 + p;
        int nb0 = idx[r0];
        dC[s]   = dist[r0];
        const float* cp = xyz + (size_t)g * 3;
        cC[s][0] = cp[0]; cC[s][1] = cp[1]; cC[s][2] = cp[2];
        const float* np = xyz + (((size_t)(g >> 12) << 12) + nb0) * 3;
        nC[s][0] = np[0]; nC[s][1] = np[1]; nC[s][2] = np[2];
        const int r1 = (g + 4) * 16 + p;
        nbN[s] = idx[r1];
        dN[s]  = dist[r1];
    }

    for (int t = 0; t < 8; ++t) {
        const int gb = gbase + 4 * t;    // first group of this batch

        // ---- 1. issue xyz loads for batch t+1 (neighbor addr from resident nbN) ----
        float cL[4][3], nL[4][3];
#pragma unroll
        for (int s = 0; s < 4; ++s) {
            const int g = (t < 7) ? gb + 4 + s : gb + s;    // clamped dummy
            const float* cp = xyz + (size_t)g * 3;
            cL[s][0] = cp[0]; cL[s][1] = cp[1]; cL[s][2] = cp[2];
            const float* np = xyz + (((size_t)(g >> 12) << 12) + nbN[s]) * 3;
            nL[s][0] = np[0]; nL[s][1] = np[1]; nL[s][2] = np[2];
        }

        // ---- 2. issue idx/dist loads for batch t+2 ----
        int nbL[4]; float dL[4];
#pragma unroll
        for (int s = 0; s < 4; ++s) {
            const int g = (t < 6) ? gb + 8 + s : gb + s;    // clamped dummy
            const int r = g * 16 + p;
            nbL[s] = idx[r];
            dL[s]  = dist[r];
        }

        // ---- 3. compute 4 groups, park each in its LDS slice ----
#pragma unroll
        for (int s = 0; s < 4; ++s) {
            bf16x8 fa;
            fa[0] = f2bf(cC[s][0]); fa[1] = f2bf(cC[s][1]); fa[2] = f2bf(cC[s][2]);
            fa[3] = f2bf(nC[s][0]); fa[4] = f2bf(nC[s][1]); fa[5] = f2bf(nC[s][2]);
            fa[6] = f2bf(dC[s]);    fa[7] = one_bf;

            f32x4 acc1[4];
#pragma unroll
            for (int tt = 0; tt < 4; ++tt) {
                acc1[tt] = (f32x4){0.f, 0.f, 0.f, 0.f};
                acc1[tt] = __builtin_amdgcn_mfma_f32_16x16x32_bf16(w1f[tt], fa, acc1[tt], 0, 0, 0);
                acc1[tt][0] = fmaxf(acc1[tt][0], 0.f);
                acc1[tt][1] = fmaxf(acc1[tt][1], 0.f);
                acc1[tt][2] = fmaxf(acc1[tt][2], 0.f);
                acc1[tt][3] = fmaxf(acc1[tt][3], 0.f);
            }

            bf16x8 hb[2];
#pragma unroll
            for (int kt = 0; kt < 2; ++kt)
#pragma unroll
                for (int j = 0; j < 8; ++j)
                    hb[kt][j] = f2bf(acc1[2 * kt + (j >> 2)][j & 3]);

            f32x4 acc2[4];
#pragma unroll
            for (int dt = 0; dt < 4; ++dt) {
                acc2[dt] = (f32x4){b2r[dt][0], b2r[dt][1], b2r[dt][2], b2r[dt][3]};
                acc2[dt] = __builtin_amdgcn_mfma_f32_16x16x32_bf16(w2f[dt][0], hb[0], acc2[dt], 0, 0, 0);
                acc2[dt] = __builtin_amdgcn_mfma_f32_16x16x32_bf16(w2f[dt][1], hb[1], acc2[dt], 0, 0, 0);
            }

            // transpose via LDS slice s (swizzled, conflict-free)
#pragma unroll
            for (int dt = 0; dt < 4; ++dt) {
                const int col = (16 * dt + 4 * u) ^ ((p & 1) << 4);
                *(f32x4*)&ws[s * 1024 + p * 64 + col] = acc2[dt];
            }
        }

        // ---- 4. store burst: 16 x NT dwordx4 back-to-back = 16 KB contiguous ----
        float* const obase = out + (size_t)gb * 1024;
#pragma unroll
        for (int i = 0; i < 16; ++i) {
            const int sl = i >> 2;
            const int pt = 4 * (i & 3) + u;
            f32x4 v = *(const f32x4*)&ws[sl * 1024 + pt * 64 + ((4 * p) ^ ((u & 1) << 4))];
            __builtin_nontemporal_store(v, (f32x4*)&obase[i * 256 + lane * 4]);
        }

        // ---- 5. rotate pipeline registers ----
#pragma unroll
        for (int s = 0; s < 4; ++s) {
            cC[s][0] = cL[s][0]; cC[s][1] = cL[s][1]; cC[s][2] = cL[s][2];
            nC[s][0] = nL[s][0]; nC[s][1] = nL[s][1]; nC[s][2] = nL[s][2];
            dC[s] = dN[s];  dN[s] = dL[s];  nbN[s] = nbL[s];
        }
    }
}

extern "C" void kernel_launch(void* const* d_in, const int* in_sizes, int n_in,
                              void* d_out, int out_size, void* d_ws, size_t ws_size,
                              hipStream_t stream) {
    const float* xyz  = (const float*)d_in[0];
    const float* dist = (const float*)d_in[1];
    const float* W1   = (const float*)d_in[2];
    const float* b1   = (const float*)d_in[3];
    const float* W2   = (const float*)d_in[4];
    const float* b2   = (const float*)d_in[5];
    const int*   idx  = (const int*)d_in[6];
    float* out = (float*)d_out;

    ppe_kernel<<<dim3(512), dim3(256), 0, stream>>>(xyz, dist, W1, b1, W2, b2, idx, out);
}

// Round 9
// 50.611 us; speedup vs baseline: 1.3564x; 1.2066x over previous
//
#include <hip/hip_runtime.h>
#include <hip/hip_bf16.h>

typedef __attribute__((ext_vector_type(8))) short bf16x8;
typedef __attribute__((ext_vector_type(4))) float f32x4;

__device__ __forceinline__ short f2bf(float x) {
    __hip_bfloat16 t = __float2bfloat16(x);
    return __builtin_bit_cast(short, t);
}

// B=16, N=4096, K=16, hidden=64, dim=64
// R9 = R5 (54.1us champion) with ONE change: stores striped 50/50 between
// the NT (no-allocate stream) path and the plain (L2 writeback) path, by
// group parity. Evidence: NT-only caps at 4.96 TB/s (=8.08 B/cy/CU) across
// every structure; plain-only ~4.0; fill proves HBM sinks 7.0. If the two
// drain paths are independent hardware, striping lets them add.

__global__ __launch_bounds__(256, 3) void ppe_kernel(
    const float* __restrict__ xyz,   // [16,4096,3]
    const float* __restrict__ dist,  // [16,4096,16]
    const float* __restrict__ W1,    // [10,64]
    const float* __restrict__ b1,    // [64]
    const float* __restrict__ W2,    // [64,64]
    const float* __restrict__ b2,    // [64]
    const int*   __restrict__ idx,   // [16,4096,16] (int32)
    float* __restrict__ out)         // [16,4096,16,64]
{
    __shared__ float sbuf[4][1024];  // 4 KB per wave, wave-private

    const int lane = threadIdx.x & 63;
    const int warp = threadIdx.x >> 6;
    const int wid  = (blockIdx.x * blockDim.x + threadIdx.x) >> 6; // 0..3071
    const int u    = lane >> 4;   // 0..3
    const int p    = lane & 15;   // 0..15

    float* const ws = &sbuf[warp][0];

    // ---- persistent weight fragments (identical to R5) ----
    bf16x8 w1f[4];
#pragma unroll
    for (int t = 0; t < 4; ++t) {
        const int hu = 16 * t + p;
#pragma unroll
        for (int j = 0; j < 8; ++j) {
            float coef;
            if (j < 3)      coef = W1[j * 64 + hu] + W1[(6 + j) * 64 + hu];
            else if (j < 6) coef = W1[j * 64 + hu] - W1[(j + 3) * 64 + hu];
            else if (j == 6) coef = W1[9 * 64 + hu];
            else             coef = b1[hu];
            w1f[t][j] = (u == 0) ? f2bf(coef) : (short)0;
        }
    }

    bf16x8 w2f[4][2];
#pragma unroll
    for (int dt = 0; dt < 4; ++dt)
#pragma unroll
        for (int kt = 0; kt < 2; ++kt)
#pragma unroll
            for (int j = 0; j < 8; ++j) {
                const int unit = 32 * kt + 16 * (j >> 2) + 4 * u + (j & 3);
                w2f[dt][kt][j] = f2bf(W2[unit * 64 + 16 * dt + p]);
            }

    float b2r[4][4];
#pragma unroll
    for (int dt = 0; dt < 4; ++dt)
#pragma unroll
        for (int r = 0; r < 4; ++r)
            b2r[dt][r] = b2[16 * dt + 4 * u + r];

    const short one_bf = f2bf(1.0f);
    const int NG = 65536, S = 3072;

    // ---- software-pipeline prologue ----
    const int g0 = wid;
    const int row0 = g0 * 16 + p;
    int   nb0 = idx[row0];
    float dC  = dist[row0];
    const float* cp0 = xyz + (size_t)g0 * 3;
    float cC0 = cp0[0], cC1 = cp0[1], cC2 = cp0[2];
    const float* np0 = xyz + ((size_t)((g0 >> 12) * 4096) + nb0) * 3;
    float nC0 = np0[0], nC1 = np0[1], nC2 = np0[2];
    int g1 = g0 + S; if (g1 >= NG) g1 = g0;
    const int row1 = g1 * 16 + p;
    int   nbN = idx[row1];
    float dN  = dist[row1];

    for (int g = g0; g < NG; g += S) {
        int gB = g + S;     if (gB >= NG) gB = g;   // t+1 (clamped dummy)
        int gA = g + 2 * S; if (gA >= NG) gA = g;   // t+2 (clamped dummy)

        // ---- 1. issue xyz loads for t+1 (neighbor addr from resident nbN) ----
        const float* cpn = xyz + (size_t)gB * 3;
        float cL0 = cpn[0], cL1 = cpn[1], cL2 = cpn[2];
        const float* npn = xyz + ((size_t)((gB >> 12) * 4096) + nbN) * 3;
        float nL0 = npn[0], nL1 = npn[1], nL2 = npn[2];

        // ---- 2. issue idx/dist loads for t+2 ----
        const int rowA = gA * 16 + p;
        int   nbL = idx[rowA];
        float dL  = dist[rowA];

        // ---- 3. layer-1 MFMA ----
        bf16x8 fa;
        fa[0] = f2bf(cC0); fa[1] = f2bf(cC1); fa[2] = f2bf(cC2);
        fa[3] = f2bf(nC0); fa[4] = f2bf(nC1); fa[5] = f2bf(nC2);
        fa[6] = f2bf(dC);  fa[7] = one_bf;

        f32x4 acc1[4];
#pragma unroll
        for (int t = 0; t < 4; ++t) {
            acc1[t] = (f32x4){0.f, 0.f, 0.f, 0.f};
            acc1[t] = __builtin_amdgcn_mfma_f32_16x16x32_bf16(w1f[t], fa, acc1[t], 0, 0, 0);
            acc1[t][0] = fmaxf(acc1[t][0], 0.f);
            acc1[t][1] = fmaxf(acc1[t][1], 0.f);
            acc1[t][2] = fmaxf(acc1[t][2], 0.f);
            acc1[t][3] = fmaxf(acc1[t][3], 0.f);
        }

        // ---- 4. layer-2 B-frag directly from acc1 (permutation-matched) ----
        bf16x8 hb[2];
#pragma unroll
        for (int kt = 0; kt < 2; ++kt)
#pragma unroll
            for (int j = 0; j < 8; ++j)
                hb[kt][j] = f2bf(acc1[2 * kt + (j >> 2)][j & 3]);

        // ---- 5. layer-2 MFMA, bias in C-init: D2[dim][pt] ----
        f32x4 acc2[4];
#pragma unroll
        for (int dt = 0; dt < 4; ++dt) {
            acc2[dt] = (f32x4){b2r[dt][0], b2r[dt][1], b2r[dt][2], b2r[dt][3]};
            acc2[dt] = __builtin_amdgcn_mfma_f32_16x16x32_bf16(w2f[dt][0], hb[0], acc2[dt], 0, 0, 0);
            acc2[dt] = __builtin_amdgcn_mfma_f32_16x16x32_bf16(w2f[dt][1], hb[1], acc2[dt], 0, 0, 0);
        }

        // ---- 6. transpose via LDS (swizzled, conflict-free) ----
#pragma unroll
        for (int dt = 0; dt < 4; ++dt) {
            const int col = (16 * dt + 4 * u) ^ ((p & 1) << 4);
            *(f32x4*)&ws[p * 64 + col] = acc2[dt];
        }

        // ---- 7. LDS -> 4x 1KB contiguous stores, striped NT/plain by parity ----
        float* const obase = out + (size_t)g * 1024;
        if (g & 1) {
#pragma unroll
            for (int i = 0; i < 4; ++i) {
                const int pt = 4 * i + u;
                f32x4 v = *(const f32x4*)&ws[pt * 64 + ((4 * p) ^ ((u & 1) << 4))];
                __builtin_nontemporal_store(v, (f32x4*)&obase[i * 256 + lane * 4]);
            }
        } else {
#pragma unroll
            for (int i = 0; i < 4; ++i) {
                const int pt = 4 * i + u;
                f32x4 v = *(const f32x4*)&ws[pt * 64 + ((4 * p) ^ ((u & 1) << 4))];
                *(f32x4*)&obase[i * 256 + lane * 4] = v;
            }
        }

        // ---- 8. rotate pipeline registers ----
        cC0 = cL0; cC1 = cL1; cC2 = cL2;
        nC0 = nL0; nC1 = nL1; nC2 = nL2;
        dC  = dN;  dN  = dL;  nbN = nbL;
    }
}

extern "C" void kernel_launch(void* const* d_in, const int* in_sizes, int n_in,
                              void* d_out, int out_size, void* d_ws, size_t ws_size,
                              hipStream_t stream) {
    const float* xyz  = (const float*)d_in[0];
    const float* dist = (const float*)d_in[1];
    const float* W1   = (const float*)d_in[2];
    const float* b1   = (const float*)d_in[3];
    const float* W2   = (const float*)d_in[4];
    const float* b2   = (const float*)d_in[5];
    const int*   idx  = (const int*)d_in[6];
    float* out = (float*)d_out;

    ppe_kernel<<<dim3(768), dim3(256), 0, stream>>>(xyz, dist, W1, b1, W2, b2, idx, out);
}

// Round 10
// 50.474 us; speedup vs baseline: 1.3601x; 1.0027x over previous
//
#include <hip/hip_runtime.h>
#include <hip/hip_bf16.h>

typedef __attribute__((ext_vector_type(8))) short bf16x8;
typedef __attribute__((ext_vector_type(4))) float f32x4;

__device__ __forceinline__ short f2bf(float x) {
    __hip_bfloat16 t = __float2bfloat16(x);
    return __builtin_bit_cast(short, t);
}

// B=16, N=4096, K=16, hidden=64, dim=64
// R10 = R9 (50.6us champion: NT/plain 50/50 stripe) with ONE change:
// stripe granularity 4KB -> 2MB ((g&1) -> ((g>>9)&1)). With stride 3072
// this is still wave-uniform & constant per wave; the collective 12MB
// write window becomes 6 alternating 2MB runs, giving each drain path
// (NT stream vs L2 writeback) long contiguous address runs instead of
// 4KB-interleaved fragments.

__global__ __launch_bounds__(256, 3) void ppe_kernel(
    const float* __restrict__ xyz,   // [16,4096,3]
    const float* __restrict__ dist,  // [16,4096,16]
    const float* __restrict__ W1,    // [10,64]
    const float* __restrict__ b1,    // [64]
    const float* __restrict__ W2,    // [64,64]
    const float* __restrict__ b2,    // [64]
    const int*   __restrict__ idx,   // [16,4096,16] (int32)
    float* __restrict__ out)         // [16,4096,16,64]
{
    __shared__ float sbuf[4][1024];  // 4 KB per wave, wave-private

    const int lane = threadIdx.x & 63;
    const int warp = threadIdx.x >> 6;
    const int wid  = (blockIdx.x * blockDim.x + threadIdx.x) >> 6; // 0..3071
    const int u    = lane >> 4;   // 0..3
    const int p    = lane & 15;   // 0..15

    float* const ws = &sbuf[warp][0];

    // ---- persistent weight fragments (identical to R5) ----
    bf16x8 w1f[4];
#pragma unroll
    for (int t = 0; t < 4; ++t) {
        const int hu = 16 * t + p;
#pragma unroll
        for (int j = 0; j < 8; ++j) {
            float coef;
            if (j < 3)      coef = W1[j * 64 + hu] + W1[(6 + j) * 64 + hu];
            else if (j < 6) coef = W1[j * 64 + hu] - W1[(j + 3) * 64 + hu];
            else if (j == 6) coef = W1[9 * 64 + hu];
            else             coef = b1[hu];
            w1f[t][j] = (u == 0) ? f2bf(coef) : (short)0;
        }
    }

    bf16x8 w2f[4][2];
#pragma unroll
    for (int dt = 0; dt < 4; ++dt)
#pragma unroll
        for (int kt = 0; kt < 2; ++kt)
#pragma unroll
            for (int j = 0; j < 8; ++j) {
                const int unit = 32 * kt + 16 * (j >> 2) + 4 * u + (j & 3);
                w2f[dt][kt][j] = f2bf(W2[unit * 64 + 16 * dt + p]);
            }

    float b2r[4][4];
#pragma unroll
    for (int dt = 0; dt < 4; ++dt)
#pragma unroll
        for (int r = 0; r < 4; ++r)
            b2r[dt][r] = b2[16 * dt + 4 * u + r];

    const short one_bf = f2bf(1.0f);
    const int NG = 65536, S = 3072;

    // ---- software-pipeline prologue ----
    const int g0 = wid;
    const int row0 = g0 * 16 + p;
    int   nb0 = idx[row0];
    float dC  = dist[row0];
    const float* cp0 = xyz + (size_t)g0 * 3;
    float cC0 = cp0[0], cC1 = cp0[1], cC2 = cp0[2];
    const float* np0 = xyz + ((size_t)((g0 >> 12) * 4096) + nb0) * 3;
    float nC0 = np0[0], nC1 = np0[1], nC2 = np0[2];
    int g1 = g0 + S; if (g1 >= NG) g1 = g0;
    const int row1 = g1 * 16 + p;
    int   nbN = idx[row1];
    float dN  = dist[row1];

    for (int g = g0; g < NG; g += S) {
        int gB = g + S;     if (gB >= NG) gB = g;   // t+1 (clamped dummy)
        int gA = g + 2 * S; if (gA >= NG) gA = g;   // t+2 (clamped dummy)

        // ---- 1. issue xyz loads for t+1 (neighbor addr from resident nbN) ----
        const float* cpn = xyz + (size_t)gB * 3;
        float cL0 = cpn[0], cL1 = cpn[1], cL2 = cpn[2];
        const float* npn = xyz + ((size_t)((gB >> 12) * 4096) + nbN) * 3;
        float nL0 = npn[0], nL1 = npn[1], nL2 = npn[2];

        // ---- 2. issue idx/dist loads for t+2 ----
        const int rowA = gA * 16 + p;
        int   nbL = idx[rowA];
        float dL  = dist[rowA];

        // ---- 3. layer-1 MFMA ----
        bf16x8 fa;
        fa[0] = f2bf(cC0); fa[1] = f2bf(cC1); fa[2] = f2bf(cC2);
        fa[3] = f2bf(nC0); fa[4] = f2bf(nC1); fa[5] = f2bf(nC2);
        fa[6] = f2bf(dC);  fa[7] = one_bf;

        f32x4 acc1[4];
#pragma unroll
        for (int t = 0; t < 4; ++t) {
            acc1[t] = (f32x4){0.f, 0.f, 0.f, 0.f};
            acc1[t] = __builtin_amdgcn_mfma_f32_16x16x32_bf16(w1f[t], fa, acc1[t], 0, 0, 0);
            acc1[t][0] = fmaxf(acc1[t][0], 0.f);
            acc1[t][1] = fmaxf(acc1[t][1], 0.f);
            acc1[t][2] = fmaxf(acc1[t][2], 0.f);
            acc1[t][3] = fmaxf(acc1[t][3], 0.f);
        }

        // ---- 4. layer-2 B-frag directly from acc1 (permutation-matched) ----
        bf16x8 hb[2];
#pragma unroll
        for (int kt = 0; kt < 2; ++kt)
#pragma unroll
            for (int j = 0; j < 8; ++j)
                hb[kt][j] = f2bf(acc1[2 * kt + (j >> 2)][j & 3]);

        // ---- 5. layer-2 MFMA, bias in C-init: D2[dim][pt] ----
        f32x4 acc2[4];
#pragma unroll
        for (int dt = 0; dt < 4; ++dt) {
            acc2[dt] = (f32x4){b2r[dt][0], b2r[dt][1], b2r[dt][2], b2r[dt][3]};
            acc2[dt] = __builtin_amdgcn_mfma_f32_16x16x32_bf16(w2f[dt][0], hb[0], acc2[dt], 0, 0, 0);
            acc2[dt] = __builtin_amdgcn_mfma_f32_16x16x32_bf16(w2f[dt][1], hb[1], acc2[dt], 0, 0, 0);
        }

        // ---- 6. transpose via LDS (swizzled, conflict-free) ----
#pragma unroll
        for (int dt = 0; dt < 4; ++dt) {
            const int col = (16 * dt + 4 * u) ^ ((p & 1) << 4);
            *(f32x4*)&ws[p * 64 + col] = acc2[dt];
        }

        // ---- 7. LDS -> 4x 1KB contiguous stores; NT/plain striped at 2MB ----
        float* const obase = out + (size_t)g * 1024;
        if ((g >> 9) & 1) {
#pragma unroll
            for (int i = 0; i < 4; ++i) {
                const int pt = 4 * i + u;
                f32x4 v = *(const f32x4*)&ws[pt * 64 + ((4 * p) ^ ((u & 1) << 4))];
                __builtin_nontemporal_store(v, (f32x4*)&obase[i * 256 + lane * 4]);
            }
        } else {
#pragma unroll
            for (int i = 0; i < 4; ++i) {
                const int pt = 4 * i + u;
                f32x4 v = *(const f32x4*)&ws[pt * 64 + ((4 * p) ^ ((u & 1) << 4))];
                *(f32x4*)&obase[i * 256 + lane * 4] = v;
            }
        }

        // ---- 8. rotate pipeline registers ----
        cC0 = cL0; cC1 = cL1; cC2 = cL2;
        nC0 = nL0; nC1 = nL1; nC2 = nL2;
        dC  = dN;  dN  = dL;  nbN = nbL;
    }
}

extern "C" void kernel_launch(void* const* d_in, const int* in_sizes, int n_in,
                              void* d_out, int out_size, void* d_ws, size_t ws_size,
                              hipStream_t stream) {
    const float* xyz  = (const float*)d_in[0];
    const float* dist = (const float*)d_in[1];
    const float* W1   = (const float*)d_in[2];
    const float* b1   = (const float*)d_in[3];
    const float* W2   = (const float*)d_in[4];
    const float* b2   = (const float*)d_in[5];
    const int*   idx  = (const int*)d_in[6];
    float* out = (float*)d_out;

    ppe_kernel<<<dim3(768), dim3(256), 0, stream>>>(xyz, dist, W1, b1, W2, b2, idx, out);
}